// Round 8
// baseline (718.146 us; speedup 1.0000x reference)
//
#include <hip/hip_runtime.h>
#include <math.h>

#define T_     8
#define WQ_    75
#define C_     640
#define HW_    100
#define WAY_   5
#define SHW_   500
#define ROWS_  7500
#define NT_    20        // K-steps (640/32)
#define EPSN   1e-12f
#define NINF   (-__builtin_inff())

typedef __bf16 bf16_t;
typedef __bf16 bf16x2 __attribute__((ext_vector_type(2)));
typedef __bf16 bf16x8 __attribute__((ext_vector_type(8)));
typedef float  f32x4  __attribute__((ext_vector_type(4)));

__device__ __forceinline__ void gld16(const bf16_t* g, bf16_t* l) {
    __builtin_amdgcn_global_load_lds(
        (const __attribute__((address_space(1))) unsigned int*)g,
        (__attribute__((address_space(3))) unsigned int*)l, 16, 0, 0);
}

#define VMCNT(N) asm volatile("s_waitcnt vmcnt(" #N ")" ::: "memory")

// sorted-triple merge: (a1>=a2>=a3) U (b1>=b2>=b3) -> top3
#define MERGE3(a1,a2,a3,b1,b2,b3)                       \
    {                                                   \
        float o1_ = fmaxf(a1,b1), c1_ = fminf(a1,b1);   \
        float h2_ = fmaxf(a2,b2), l2_ = fminf(a2,b2);   \
        float h3_ = fmaxf(a3,b3);                       \
        a1 = o1_;                                       \
        float n2_ = fmaxf(c1_, h2_);                    \
        a3 = fmaxf(fmaxf(l2_, h3_), fminf(c1_, h2_));   \
        a2 = n2_;                                       \
    }

// ---------------------------------------------------------------------------
// Fused prep: grid 4000 chunk-blocks x 256 threads.
//  bid < 3000: q-chunk (tq = bid/5, c0 = (bid%5)*128):
//      Qn[tq][p][c] = query[tq][c][p] / ||query[tq][c][:]||   (norm over p)
//  bid >= 3000: s-chunk (tu, c0):
//      Sn[tu][p][c] = sup[tu][c][p] / ||sup[tu][:][p]||       (norm over c,
//      recomputed per chunk from global — L2-shared across sibling chunks)
// 128x100 f32 LDS tile, rows padded to 101 (no pow-2 bank stride).
// ---------------------------------------------------------------------------
__global__ __launch_bounds__(256) void prep(const float* __restrict__ query,
                                            const float* __restrict__ sup,
                                            bf16_t* __restrict__ Qn,
                                            bf16_t* __restrict__ Sn) {
    __shared__ float tile[128 * 101];        // 51.7 KB
    __shared__ float inv[128];
    __shared__ float part[2][HW_];
    const int tid = threadIdx.x;
    const int bid = blockIdx.x;
    const bool isq = (bid < 3000);
    const int map = isq ? bid / 5 : (bid - 3000) / 5;
    const int c0  = (isq ? bid % 5 : (bid - 3000) % 5) * 128;

    const float* src = (isq ? query : sup) + (size_t)map * C_ * HW_;
    bf16_t*      dst = (isq ? Qn : Sn) + (size_t)map * HW_ * C_;

    // stage 128x100 chunk, coalesced float4 (100%4==0: no row-crossing)
    const float4* s4 = (const float4*)(src + (size_t)c0 * HW_);
    for (int j = tid; j < 3200; j += 256) {
        float4 v = s4[j];
        int f = j * 4;
        int c = f / 100, p = f - c * 100;
        float* d = &tile[c * 101 + p];
        d[0] = v.x; d[1] = v.y; d[2] = v.z; d[3] = v.w;
    }

    if (isq) {
        __syncthreads();
        // per-c norm over p, 2 lanes per c
        {
            int c = tid >> 1, g = tid & 1;
            float s = 0.f;
            #pragma unroll 10
            for (int p = g * 50; p < g * 50 + 50; ++p) {
                float x = tile[c * 101 + p];
                s = fmaf(x, x, s);
            }
            s += __shfl_xor(s, 1);
            if (g == 0) inv[c] = 1.f / fmaxf(sqrtf(s), EPSN);
        }
        __syncthreads();
        for (int j = tid; j < 6400; j += 256) {
            int p  = j >> 6;
            int cl = (j & 63) * 2;
            bf16x2 v;
            v.x = (bf16_t)(tile[cl * 101 + p] * inv[cl]);
            v.y = (bf16_t)(tile[(cl + 1) * 101 + p] * inv[cl + 1]);
            *(bf16x2*)(dst + (size_t)p * C_ + c0 + cl) = v;
        }
    } else {
        // per-p norm over ALL c (global pass, coalesced; L2-hot for siblings)
        {
            int l = tid & 127, grp = tid >> 7;
            float s = 0.f;
            if (l < HW_) {
                #pragma unroll 8
                for (int c = grp; c < C_; c += 2) {
                    float x = src[(size_t)c * HW_ + l];
                    s = fmaf(x, x, s);
                }
                part[grp][l] = s;
            }
        }
        __syncthreads();
        if (tid < HW_)
            inv[tid] = 1.f / fmaxf(sqrtf(part[0][tid] + part[1][tid]), EPSN);
        __syncthreads();
        for (int j = tid; j < 6400; j += 256) {
            int p  = j >> 6;
            int cl = (j & 63) * 2;
            float iv = inv[p];
            bf16x2 v;
            v.x = (bf16_t)(tile[cl * 101 + p] * iv);
            v.y = (bf16_t)(tile[(cl + 1) * 101 + p] * iv);
            *(bf16x2*)(dst + (size_t)p * C_ + c0 + cl) = v;
        }
    }
}

// ---------------------------------------------------------------------------
// Main MFMA kernel: per (row-tile, t, w): rel (64 x 512[500]) over K=640,
// fused per-row top-3 + atomicAdd into score.
// 256 threads = 4 waves, wave tile 64x128 (4 M x 8 N frags, 16x16x32).
// T3/T4 pipeline: double-buffered LDS, counted s_waitcnt vmcnt(9) (9 gld16
// per wave per tile, uniform), raw s_barrier, setprio around MFMA cluster.
// ---------------------------------------------------------------------------
__global__ __launch_bounds__(256) void dn4_mfma(const bf16_t* __restrict__ Qn,
                                                const bf16_t* __restrict__ Sn,
                                                float* __restrict__ score) {
    __shared__ bf16_t As0[64 * 32], As1[64 * 32];    // 4+4 KB
    __shared__ bf16_t Bs0[512 * 32], Bs1[512 * 32];  // 32+32 KB
    __shared__ float  topL[64][4][3];                // 3 KB  (75 KB: 2 blk/CU)

    const int t = blockIdx.y, w = blockIdx.z;
    const int rbase = blockIdx.x * 64;
    const int tid = threadIdx.x;
    const int l = tid & 63, wid = tid >> 6;  // 4 waves
    const int fr = l & 15, fq = l >> 4;
    const int wc = wid;

    const bf16_t* Qt = Qn + (size_t)t * ROWS_ * C_;
    const bf16_t* St = Sn + ((size_t)t * 2500 + (size_t)w * SHW_) * C_;

    // ---- staging addressing (LDS dest linear: waveBase + lane*16B) ----
    const int arow = (wid << 4) + (l >> 2);          // LDS A row 0..63
    const int aswz = (l & 3) ^ ((arow >> 1) & 3);    // source slot swizzle
    int agr = rbase + arow; if (agr > ROWS_ - 1) agr = ROWS_ - 1;
    const bf16_t* asrc = Qt + (size_t)agr * C_ + aswz * 8;

    const int bswz = (l & 3) ^ ((l >> 3) & 3);
    int bgo[8];
    #pragma unroll
    for (int j = 0; j < 8; ++j) {
        int n = wid * 128 + j * 16 + (l >> 2);
        if (n > SHW_ - 1) n = SHW_ - 1;
        bgo[j] = n * C_ + bswz * 8;
    }

    // ---- fragment LDS offsets (kt-invariant) ----
    int aoff[4], boff[8];
    #pragma unroll
    for (int mi = 0; mi < 4; ++mi) {
        int row = mi * 16 + fr;
        aoff[mi] = row * 32 + (fq ^ ((row >> 1) & 3)) * 8;
    }
    #pragma unroll
    for (int ni = 0; ni < 8; ++ni) {
        int n = wc * 128 + ni * 16 + fr;
        boff[ni] = n * 32 + (fq ^ ((n >> 1) & 3)) * 8;
    }

    f32x4 acc[4][8];
    #pragma unroll
    for (int mi = 0; mi < 4; ++mi)
        #pragma unroll
        for (int ni = 0; ni < 8; ++ni)
            acc[mi][ni] = (f32x4){0.f, 0.f, 0.f, 0.f};

#define STAGE(KO, AD, BD)                                          \
    {                                                              \
        gld16(asrc + (KO), (AD) + wid * 512);                      \
        _Pragma("unroll")                                          \
        for (int j_ = 0; j_ < 8; ++j_)                             \
            gld16(St + bgo[j_] + (KO), (BD) + (wid * 8 + j_) * 512); \
    }

#define COMPUTE(AC, BC)                                            \
    {                                                              \
        bf16x8 av[4], bv[8];                                       \
        _Pragma("unroll")                                          \
        for (int mi = 0; mi < 4; ++mi)                             \
            av[mi] = *(const bf16x8*)((AC) + aoff[mi]);            \
        _Pragma("unroll")                                          \
        for (int ni = 0; ni < 8; ++ni)                             \
            bv[ni] = *(const bf16x8*)((BC) + boff[ni]);            \
        __builtin_amdgcn_s_setprio(1);                             \
        _Pragma("unroll")                                          \
        for (int mi = 0; mi < 4; ++mi)                             \
            _Pragma("unroll")                                      \
            for (int ni = 0; ni < 8; ++ni)                         \
                acc[mi][ni] = __builtin_amdgcn_mfma_f32_16x16x32_bf16( \
                    av[mi], bv[ni], acc[mi][ni], 0, 0, 0);         \
        __builtin_amdgcn_s_setprio(0);                             \
    }

    // prologue: stage tile 0
    STAGE(0, As0, Bs0);

    bf16_t *Ac = As0, *An = As1, *Bc = Bs0, *Bn = Bs1;
    for (int kt = 0; kt < NT_ - 1; ++kt) {
        STAGE((kt + 1) * 32, An, Bn);    // next tile: stays in flight
        VMCNT(9);                         // wait ONLY current tile's 9 loads
        __builtin_amdgcn_s_barrier();
        __builtin_amdgcn_sched_barrier(0);
        COMPUTE(Ac, Bc);
        __builtin_amdgcn_s_barrier();     // readers done -> next overwrite ok
        bf16_t* tp;
        tp = Ac; Ac = An; An = tp;
        tp = Bc; Bc = Bn; Bn = tp;
    }
    VMCNT(0);                             // last tile: full drain
    __builtin_amdgcn_s_barrier();
    __builtin_amdgcn_sched_barrier(0);
    COMPUTE(Ac, Bc);

#undef STAGE
#undef COMPUTE

    // ---- fused top-3 epilogue ----
    // C/D layout: col = wc*128 + ni*16 + fr, row = mi*16 + fq*4 + j
    __syncthreads();
    #pragma unroll
    for (int mi = 0; mi < 4; ++mi) {
        #pragma unroll
        for (int j = 0; j < 4; ++j) {
            float t1 = NINF, t2 = NINF, t3 = NINF;
            #pragma unroll
            for (int ni = 0; ni < 8; ++ni) {
                int gc = wc * 128 + ni * 16 + fr;
                float v = (gc < SHW_) ? acc[mi][ni][j] : NINF;
                float m1 = fmaxf(t1, v),  n1 = fminf(t1, v);
                float m2 = fmaxf(t2, n1), n2 = fminf(t2, n1);
                t1 = m1; t2 = m2; t3 = fmaxf(t3, n2);
            }
            #pragma unroll
            for (int d = 1; d < 16; d <<= 1) {
                float b1 = __shfl_xor(t1, d);
                float b2 = __shfl_xor(t2, d);
                float b3 = __shfl_xor(t3, d);
                MERGE3(t1, t2, t3, b1, b2, b3);
            }
            if (fr == 0) {
                int lrow = mi * 16 + fq * 4 + j;
                topL[lrow][wc][0] = t1;
                topL[lrow][wc][1] = t2;
                topL[lrow][wc][2] = t3;
            }
        }
    }
    __syncthreads();

    if (tid < 64) {
        float a1 = topL[tid][0][0], a2 = topL[tid][0][1], a3 = topL[tid][0][2];
        #pragma unroll
        for (int g = 1; g < 4; ++g) {
            float b1 = topL[tid][g][0], b2 = topL[tid][g][1], b3 = topL[tid][g][2];
            MERGE3(a1, a2, a3, b1, b2, b3);
        }
        int r = rbase + tid;
        if (r < ROWS_) {
            int q = r / 100;
            atomicAdd(score + ((size_t)(t * WQ_ + q) * WAY_ + w), a1 + a2 + a3);
        }
    }
}

// ---------------------------------------------------------------------------
extern "C" void kernel_launch(void* const* d_in, const int* in_sizes, int n_in,
                              void* d_out, int out_size, void* d_ws, size_t ws_size,
                              hipStream_t stream) {
    const float* query   = (const float*)d_in[0];   // (8,75,640,10,10)
    const float* support = (const float*)d_in[1];   // (8,25,640,10,10)
    bf16_t* Qn = (bf16_t*)d_ws;                     // 60000 x 640 bf16 = 76.8 MB
    bf16_t* Sn = Qn + (size_t)T_ * ROWS_ * C_;      // 20000 x 640 bf16 = 25.6 MB
    float* score = (float*)d_out;                   // 8*75*5

    hipMemsetAsync(d_out, 0, (size_t)out_size * sizeof(float), stream);

    hipLaunchKernelGGL(prep, dim3(4000), dim3(256), 0, stream,
                       query, support, Qn, Sn);
    hipLaunchKernelGGL(dn4_mfma, dim3((ROWS_ + 63) / 64, T_, WAY_), dim3(256),
                       0, stream, Qn, Sn, score);
}